// Round 1
// baseline (529.308 us; speedup 1.0000x reference)
//
#include <hip/hip_runtime.h>
#include <hip/hip_bf16.h>
#include <cmath>
#include <cstdint>

// Problem dims (fixed by the reference)
#define BB 4
#define SS 2048
#define DD 1024
#define HH 16
#define MM (BB * SS)   // 8192 tokens

typedef __attribute__((ext_vector_type(8))) __bf16 bf16x8;
typedef __attribute__((ext_vector_type(4))) float f32x4;
typedef __attribute__((ext_vector_type(8))) float f32x8;
typedef __attribute__((ext_vector_type(8))) unsigned short u16x8;

__device__ __forceinline__ unsigned short f2bu(float f) {
  __hip_bfloat16 h = __float2bfloat16(f);
  return __builtin_bit_cast(unsigned short, h);
}

__device__ __forceinline__ f32x4 mfma16(bf16x8 a, bf16x8 b, f32x4 c) {
  return __builtin_amdgcn_mfma_f32_16x16x32_bf16(a, b, c, 0, 0, 0);
}

#define GLD16(gp, lp) __builtin_amdgcn_global_load_lds(                     \
    (const __attribute__((address_space(1))) void*)(gp),                    \
    (__attribute__((address_space(3))) void*)(lp), 16, 0, 0)

// ---------------- prep: fp32 -> bf16 cast (vectorized) ----------------
__global__ __launch_bounds__(256) void k_cast_bf16(const float* __restrict__ in,
                                                   unsigned short* __restrict__ out,
                                                   int n) {
  int i = (blockIdx.x * 256 + threadIdx.x) * 8;
  if (i >= n) return;
  f32x8 v = *(const f32x8*)(in + i);
  u16x8 o;
#pragma unroll
  for (int j = 0; j < 8; ++j) o[j] = f2bu(v[j]);
  *(u16x8*)(out + i) = o;
}

// ---------------- prep: transpose + cast  in[R][C] f32 -> out[C][R] bf16 ----------------
__global__ __launch_bounds__(256) void k_transpose_bf16(const float* __restrict__ in,
                                                        unsigned short* __restrict__ out,
                                                        int R, int C) {
  __shared__ float tile[32][33];
  const int c0 = blockIdx.x * 32, r0 = blockIdx.y * 32;
  const int tx = threadIdx.x & 31, ty = threadIdx.x >> 5;  // ty 0..7
#pragma unroll
  for (int i = ty; i < 32; i += 8)
    tile[i][tx] = in[(size_t)(r0 + i) * C + c0 + tx];
  __syncthreads();
#pragma unroll
  for (int i = ty; i < 32; i += 8)
    out[(size_t)(c0 + i) * R + r0 + tx] = f2bu(tile[tx][i]);
}

// ---------------- bf16 GEMM, m97 structure ----------------
// C[M][N] = A[M][K] * Bt[N][K]^T + bias[N]
// 128x128 tile, BK=64, 4 waves, each wave -> 64x64 (acc[4][4] of 16x16 frags)
template <int OUT_F32>
__global__ __launch_bounds__(256) void k_gemm_bt(const unsigned short* __restrict__ A,
                                                 const unsigned short* __restrict__ Bt,
                                                 const float* __restrict__ bias,
                                                 void* __restrict__ Cout,
                                                 int M, int N, int K) {
  __shared__ __attribute__((aligned(16))) unsigned short lA[128 * 64];
  __shared__ __attribute__((aligned(16))) unsigned short lB[128 * 64];
  const int tid = threadIdx.x;
  const int wave = tid >> 6, lane = tid & 63;
  const int g = lane >> 4, c = lane & 15;
  const int wr = wave >> 1, wc = wave & 1;
  const int m0 = blockIdx.y * 128, n0 = blockIdx.x * 128;
  const int srow = lane >> 3, scol = (lane & 7) * 8;

  f32x4 acc[4][4] = {};

  for (int k0 = 0; k0 < K; k0 += 64) {
#pragma unroll
    for (int i = 0; i < 4; ++i) {
      const int chunk = i * 4 + wave;  // wave-uniform
      GLD16(A + (size_t)(m0 + chunk * 8 + srow) * K + k0 + scol, lA + chunk * 512);
      GLD16(Bt + (size_t)(n0 + chunk * 8 + srow) * K + k0 + scol, lB + chunk * 512);
    }
    __syncthreads();
#pragma unroll
    for (int kk = 0; kk < 2; ++kk) {
      bf16x8 af[4], bfr[4];
#pragma unroll
      for (int mi = 0; mi < 4; ++mi)
        af[mi] = *(const bf16x8*)&lA[(wr * 64 + mi * 16 + c) * 64 + kk * 32 + g * 8];
#pragma unroll
      for (int ni = 0; ni < 4; ++ni)
        bfr[ni] = *(const bf16x8*)&lB[(wc * 64 + ni * 16 + c) * 64 + kk * 32 + g * 8];
#pragma unroll
      for (int mi = 0; mi < 4; ++mi)
#pragma unroll
        for (int ni = 0; ni < 4; ++ni)
          acc[mi][ni] = mfma16(af[mi], bfr[ni], acc[mi][ni]);
    }
    __syncthreads();
  }

#pragma unroll
  for (int mi = 0; mi < 4; ++mi)
#pragma unroll
    for (int ni = 0; ni < 4; ++ni) {
      const int col = n0 + wc * 64 + ni * 16 + c;
      const float bv = bias[col];
#pragma unroll
      for (int r = 0; r < 4; ++r) {
        const int row = m0 + wr * 64 + mi * 16 + g * 4 + r;
        const float v = acc[mi][ni][r] + bv;
        if (OUT_F32)
          ((float*)Cout)[(size_t)row * N + col] = v;
        else
          ((unsigned short*)Cout)[(size_t)row * N + col] = f2bu(v);
      }
    }
}

// ---------------- causal flash attention ----------------
// qkv: [B*S][3072] bf16 (Q at col 0, K at 1024, V at 2048; head h at h*64)
// y:   [B*S][1024] bf16
// Block: 64 Q rows (4 waves x 16 rows), iterate K/V in blocks of 32.
__global__ __launch_bounds__(256) void k_attn(const unsigned short* __restrict__ qkv,
                                              unsigned short* __restrict__ y) {
  __shared__ __attribute__((aligned(16))) unsigned short lK[32 * 72];      // K row-major, pad 72
  __shared__ __attribute__((aligned(16))) unsigned short lV[64 * 40];      // V^T [d][key], pad 40
  __shared__ __attribute__((aligned(16))) unsigned short lP[4][16 * 40];   // per-wave P [q][key]

  const int tid = threadIdx.x, wave = tid >> 6, lane = tid & 63;
  const int g = lane >> 4, c = lane & 15;
  const int qt = blockIdx.x, bh = blockIdx.y;
  const int b = bh >> 4, h = bh & 15;
  const size_t rb = (size_t)b * SS;
  const int qw = qt * 64 + wave * 16;  // this wave's first Q row (within sequence)

  // Q fragments in registers: A[m=c][k=hd], hd halves 0-31 / 32-63
  bf16x8 qf[2];
  {
    const unsigned short* qp = qkv + (rb + qw + c) * 3072 + h * 64 + g * 8;
    qf[0] = *(const bf16x8*)qp;
    qf[1] = *(const bf16x8*)(qp + 32);
  }

  float m_run[4], l_run[4];
  f32x4 o[4] = {};
#pragma unroll
  for (int r = 0; r < 4; ++r) { m_run[r] = -INFINITY; l_run[r] = 0.f; }

  const int srow = tid >> 3, scol = (tid & 7) * 8;
  const int nkb = qt * 2 + 2;

  for (int kb = 0; kb < nkb; ++kb) {
    const int k0 = kb * 32;
    {  // stage K rows [k0, k0+32) and V^T
      const size_t base = (rb + k0 + srow) * 3072 + h * 64 + scol;
      u16x8 kv = *(const u16x8*)(qkv + base + 1024);
      *(u16x8*)&lK[srow * 72 + scol] = kv;
      u16x8 vv = *(const u16x8*)(qkv + base + 2048);
#pragma unroll
      for (int j = 0; j < 8; ++j) lV[(scol + j) * 40 + srow] = vv[j];
    }
    __syncthreads();

    if (k0 <= qw + 15) {  // wave-uniform: tile not fully masked for this wave
      // S = Q K^T : D row = q (4g+r), col = key (c + 16*nb)
      f32x4 s0 = {}, s1 = {};
      {
        const int r0 = c * 72 + g * 8, r1 = (c + 16) * 72 + g * 8;
        s0 = mfma16(qf[0], *(const bf16x8*)&lK[r0], s0);
        s0 = mfma16(qf[1], *(const bf16x8*)&lK[r0 + 32], s0);
        s1 = mfma16(qf[0], *(const bf16x8*)&lK[r1], s1);
        s1 = mfma16(qf[1], *(const bf16x8*)&lK[r1 + 32], s1);
      }
      float p0[4], p1[4];
#pragma unroll
      for (int r = 0; r < 4; ++r) {
        const int q = qw + g * 4 + r;
        float v0 = (k0 + c > q) ? -INFINITY : s0[r] * 0.125f;
        float v1 = (k0 + 16 + c > q) ? -INFINITY : s1[r] * 0.125f;
        float mx = fmaxf(v0, v1);
#pragma unroll
        for (int msk = 1; msk < 16; msk <<= 1) mx = fmaxf(mx, __shfl_xor(mx, msk));
        const float mn = fmaxf(m_run[r], mx);
        const float alpha = __expf(m_run[r] - mn);  // m_run=-inf -> 0; mn always finite
        m_run[r] = mn;
        p0[r] = __expf(v0 - mn);
        p1[r] = __expf(v1 - mn);
        float rs = p0[r] + p1[r];
#pragma unroll
        for (int msk = 1; msk < 16; msk <<= 1) rs += __shfl_xor(rs, msk);
        l_run[r] = alpha * l_run[r] + rs;
#pragma unroll
        for (int db = 0; db < 4; ++db) o[db][r] *= alpha;
      }
      // P (D layout) -> per-wave LDS -> re-read as A fragment (transpose)
#pragma unroll
      for (int r = 0; r < 4; ++r) {
        lP[wave][(g * 4 + r) * 40 + c] = f2bu(p0[r]);
        lP[wave][(g * 4 + r) * 40 + 16 + c] = f2bu(p1[r]);
      }
      asm volatile("s_waitcnt lgkmcnt(0)" ::: "memory");
      __builtin_amdgcn_sched_barrier(0);
      const bf16x8 pf = *(const bf16x8*)&lP[wave][c * 40 + g * 8];
#pragma unroll
      for (int db = 0; db < 4; ++db) {
        const bf16x8 vf = *(const bf16x8*)&lV[(c + 16 * db) * 40 + g * 8];
        o[db] = mfma16(pf, vf, o[db]);
      }
    }
    __syncthreads();
  }

#pragma unroll
  for (int r = 0; r < 4; ++r) {
    const float inv = 1.f / l_run[r];
    const int row = qw + g * 4 + r;
#pragma unroll
    for (int db = 0; db < 4; ++db)
      y[(rb + row) * 1024 + h * 64 + db * 16 + c] = f2bu(o[db][r] * inv);
  }
}

// ---------------- launch ----------------
extern "C" void kernel_launch(void* const* d_in, const int* in_sizes, int n_in,
                              void* d_out, int out_size, void* d_ws, size_t ws_size,
                              hipStream_t stream) {
  (void)in_sizes; (void)n_in; (void)out_size; (void)ws_size;
  const float* x     = (const float*)d_in[0];
  const float* w_qkv = (const float*)d_in[1];
  const float* b_qkv = (const float*)d_in[2];
  const float* w_out = (const float*)d_in[3];
  const float* b_out = (const float*)d_in[4];
  float* out = (float*)d_out;

  char* ws = (char*)d_ws;
  unsigned short* x_bf  = (unsigned short*)(ws);                       // 16 MB (reused for y)
  unsigned short* wqkvT = (unsigned short*)(ws + (size_t)16 * 1048576); // 6 MB
  unsigned short* woutT = (unsigned short*)(ws + (size_t)22 * 1048576); // 2 MB
  unsigned short* qkv   = (unsigned short*)(ws + (size_t)24 * 1048576); // 48 MB -> total 72 MB

  // prep
  k_cast_bf16<<<dim3((MM * DD) / (256 * 8)), 256, 0, stream>>>(x, x_bf, MM * DD);
  k_transpose_bf16<<<dim3(3 * DD / 32, DD / 32), 256, 0, stream>>>(w_qkv, wqkvT, DD, 3 * DD);
  k_transpose_bf16<<<dim3(DD / 32, DD / 32), 256, 0, stream>>>(w_out, woutT, DD, DD);

  // QKV projection: [8192,3072] bf16
  k_gemm_bt<0><<<dim3(3 * DD / 128, MM / 128), 256, 0, stream>>>(
      x_bf, wqkvT, b_qkv, qkv, MM, 3 * DD, DD);

  // causal attention -> y (bf16, reuses x_bf region)
  k_attn<<<dim3(SS / 64, BB * HH), 256, 0, stream>>>(qkv, x_bf);

  // output projection: fp32 out
  k_gemm_bt<1><<<dim3(DD / 128, MM / 128), 256, 0, stream>>>(
      x_bf, woutT, b_out, out, MM, DD, DD);
}

// Round 2
// 298.187 us; speedup vs baseline: 1.7751x; 1.7751x over previous
//
#include <hip/hip_runtime.h>
#include <hip/hip_bf16.h>
#include <cmath>
#include <cstdint>

// Problem dims (fixed by the reference)
#define BB 4
#define SS 2048
#define DD 1024
#define HH 16
#define MM (BB * SS)   // 8192 tokens

// softmax scale folded into Q weight columns: (1/sqrt(64)) * log2(e)
#define ATT_C 0.18033688011112042f

typedef __attribute__((ext_vector_type(8))) __bf16 bf16x8;
typedef __attribute__((ext_vector_type(4))) float f32x4;
typedef __attribute__((ext_vector_type(8))) float f32x8;
typedef __attribute__((ext_vector_type(8))) unsigned short u16x8;
typedef __attribute__((ext_vector_type(2))) unsigned int u32x2;
typedef __attribute__((ext_vector_type(4))) unsigned int u32x4;

__device__ __forceinline__ unsigned short f2bu(float f) {
  __hip_bfloat16 h = __float2bfloat16(f);
  return __builtin_bit_cast(unsigned short, h);
}

__device__ __forceinline__ f32x4 mfma16(bf16x8 a, bf16x8 b, f32x4 c) {
  return __builtin_amdgcn_mfma_f32_16x16x32_bf16(a, b, c, 0, 0, 0);
}

#define GLD16(gp, lp) __builtin_amdgcn_global_load_lds(                     \
    (const __attribute__((address_space(1))) void*)(gp),                    \
    (__attribute__((address_space(3))) void*)(lp), 16, 0, 0)

// ---------------- prep: fp32 -> bf16 cast (vectorized) ----------------
__global__ __launch_bounds__(256) void k_cast_bf16(const float* __restrict__ in,
                                                   unsigned short* __restrict__ out,
                                                   int n) {
  int i = (blockIdx.x * 256 + threadIdx.x) * 8;
  if (i >= n) return;
  f32x8 v = *(const f32x8*)(in + i);
  u16x8 o;
#pragma unroll
  for (int j = 0; j < 8; ++j) o[j] = f2bu(v[j]);
  *(u16x8*)(out + i) = o;
}

// ---------------- prep: transpose + cast  in[R][C] f32 -> out[C][R] bf16 ----------------
// output rows < scale_end get multiplied by scale (folds softmax scale into Q weights)
__global__ __launch_bounds__(256) void k_transpose_bf16(const float* __restrict__ in,
                                                        unsigned short* __restrict__ out,
                                                        int R, int C,
                                                        float scale, int scale_end) {
  __shared__ float tile[32][33];
  const int c0 = blockIdx.x * 32, r0 = blockIdx.y * 32;
  const int tx = threadIdx.x & 31, ty = threadIdx.x >> 5;  // ty 0..7
#pragma unroll
  for (int i = ty; i < 32; i += 8)
    tile[i][tx] = in[(size_t)(r0 + i) * C + c0 + tx];
  __syncthreads();
#pragma unroll
  for (int i = ty; i < 32; i += 8) {
    float v = tile[tx][i];
    if (c0 + i < scale_end) v *= scale;
    out[(size_t)(c0 + i) * R + r0 + tx] = f2bu(v);
  }
}

// ---------------- bf16 GEMM, m97 structure ----------------
// C[M][N] = A[M][K] * Bt[N][K]^T + bias[N]  (bias cols < bias_scale_end scaled by ATT_C)
template <int OUT_F32>
__global__ __launch_bounds__(256) void k_gemm_bt(const unsigned short* __restrict__ A,
                                                 const unsigned short* __restrict__ Bt,
                                                 const float* __restrict__ bias,
                                                 void* __restrict__ Cout,
                                                 int M, int N, int K, int bias_scale_end) {
  __shared__ __attribute__((aligned(16))) unsigned short lA[128 * 64];
  __shared__ __attribute__((aligned(16))) unsigned short lB[128 * 64];
  const int tid = threadIdx.x;
  const int wave = tid >> 6, lane = tid & 63;
  const int g = lane >> 4, c = lane & 15;
  const int wr = wave >> 1, wc = wave & 1;
  const int m0 = blockIdx.y * 128, n0 = blockIdx.x * 128;
  const int srow = lane >> 3, scol = (lane & 7) * 8;

  f32x4 acc[4][4] = {};

  for (int k0 = 0; k0 < K; k0 += 64) {
#pragma unroll
    for (int i = 0; i < 4; ++i) {
      const int chunk = i * 4 + wave;  // wave-uniform
      GLD16(A + (size_t)(m0 + chunk * 8 + srow) * K + k0 + scol, lA + chunk * 512);
      GLD16(Bt + (size_t)(n0 + chunk * 8 + srow) * K + k0 + scol, lB + chunk * 512);
    }
    __syncthreads();
#pragma unroll
    for (int kk = 0; kk < 2; ++kk) {
      bf16x8 af[4], bfr[4];
#pragma unroll
      for (int mi = 0; mi < 4; ++mi)
        af[mi] = *(const bf16x8*)&lA[(wr * 64 + mi * 16 + c) * 64 + kk * 32 + g * 8];
#pragma unroll
      for (int ni = 0; ni < 4; ++ni)
        bfr[ni] = *(const bf16x8*)&lB[(wc * 64 + ni * 16 + c) * 64 + kk * 32 + g * 8];
#pragma unroll
      for (int mi = 0; mi < 4; ++mi)
#pragma unroll
        for (int ni = 0; ni < 4; ++ni)
          acc[mi][ni] = mfma16(af[mi], bfr[ni], acc[mi][ni]);
    }
    __syncthreads();
  }

#pragma unroll
  for (int mi = 0; mi < 4; ++mi)
#pragma unroll
    for (int ni = 0; ni < 4; ++ni) {
      const int col = n0 + wc * 64 + ni * 16 + c;
      float bv = bias[col];
      if (col < bias_scale_end) bv *= ATT_C;
#pragma unroll
      for (int r = 0; r < 4; ++r) {
        const int row = m0 + wr * 64 + mi * 16 + g * 4 + r;
        const float v = acc[mi][ni][r] + bv;
        if (OUT_F32)
          ((float*)Cout)[(size_t)row * N + col] = v;
        else
          ((unsigned short*)Cout)[(size_t)row * N + col] = f2bu(v);
      }
    }
}

// ---------------- causal flash attention (swapped QK^T, tr-read PV) ----------------
// qkv: [B*S][3072] bf16 (Q at 0 pre-scaled by ATT_C, K at 1024, V at 2048; head h at h*64)
// y:   [B*S][1024] bf16
// Block: 4 waves x 32 Q rows = 128 rows. KVBLK=64, double-buffered LDS.
// K LDS layout: chunk-major — 16B chunk (gcol,row) at (gcol*64+row)*16B.
// V LDS layout: tr-subtiled — subtile (dc,k4) = keys 4k4..+3 x d 16dc..+15 row-major at (dc*16+k4)*128B.
__global__ __launch_bounds__(256) void k_attn(const unsigned short* __restrict__ qkv,
                                              unsigned short* __restrict__ y) {
  __shared__ __attribute__((aligned(16))) unsigned short lK[2][4096];
  __shared__ __attribute__((aligned(16))) unsigned short lV[2][4096];

  const int tid = threadIdx.x, wave = tid >> 6, lane = tid & 63;
  const int g = lane >> 4, c = lane & 15;
  const int qt = 15 - (int)blockIdx.x;        // longest blocks first
  const int bh = blockIdx.y, b = bh >> 4, hc = bh & 15;
  const size_t rb = (size_t)b * SS;
  const int qw = qt * 128 + wave * 32;        // wave's first q row

  // Q B-frags (scale pre-folded into weights): B[col=q=c][k=hd]
  bf16x8 qf[2][2];
#pragma unroll
  for (int m = 0; m < 2; ++m)
#pragma unroll
    for (int kh = 0; kh < 2; ++kh)
      qf[m][kh] = *(const bf16x8*)(qkv + (rb + qw + m * 16 + c) * 3072 + hc * 64 + kh * 32 + g * 8);

  float mrun[2] = {-INFINITY, -INFINITY};
  float lrun[2] = {0.f, 0.f};
  f32x4 o[2][4] = {};

  const int nkb = 2 * qt + 2;

#define STAGE(buf, kb) do {                                                              \
    const int k0s = (kb) * 64;                                                           \
    const int nb0 = wave * 64, n0_ = nb0 + lane;                                         \
    GLD16(qkv + (rb + k0s + (n0_ & 63)) * 3072 + 1024 + hc * 64 + (n0_ >> 6) * 8,        \
          &lK[buf][0] + nb0 * 8);                                                        \
    GLD16(qkv + (rb + k0s + 4 * ((n0_ >> 3) & 15) + ((n0_ >> 1) & 3)) * 3072 + 2048      \
              + hc * 64 + (n0_ >> 7) * 16 + (n0_ & 1) * 8,                               \
          &lV[buf][0] + nb0 * 8);                                                        \
    const int nb1 = 256 + wave * 64, n1_ = nb1 + lane;                                   \
    GLD16(qkv + (rb + k0s + (n1_ & 63)) * 3072 + 1024 + hc * 64 + (n1_ >> 6) * 8,        \
          &lK[buf][0] + nb1 * 8);                                                        \
    GLD16(qkv + (rb + k0s + 4 * ((n1_ >> 3) & 15) + ((n1_ >> 1) & 3)) * 3072 + 2048      \
              + hc * 64 + (n1_ >> 7) * 16 + (n1_ & 1) * 8,                               \
          &lV[buf][0] + nb1 * 8);                                                        \
  } while (0)

#define TRRD(dst, OFFLIT) \
  asm volatile("ds_read_b64_tr_b16 %0, %1 offset:" OFFLIT : "=v"(dst) : "v"(vp))

  auto pv_mma = [&](f32x4 (&s)[2][4], u32x2 (&tr)[4][2], int kh) {
    // P A-frag: k-slot 8g+j <-> key = (2kh + j/4)*16 + 4g + (j&3) — lane-local
    bf16x8 pa[2];
#pragma unroll
    for (int m = 0; m < 2; ++m) {
      u16x8 t;
#pragma unroll
      for (int j = 0; j < 4; ++j) {
        t[j]     = f2bu(s[m][2 * kh][j]);
        t[4 + j] = f2bu(s[m][2 * kh + 1][j]);
      }
      pa[m] = __builtin_bit_cast(bf16x8, t);
    }
#pragma unroll
    for (int dc = 0; dc < 4; ++dc) {
      u32x4 vv = {tr[dc][0][0], tr[dc][0][1], tr[dc][1][0], tr[dc][1][1]};
      const bf16x8 vf = __builtin_bit_cast(bf16x8, vv);
#pragma unroll
      for (int m = 0; m < 2; ++m)
        o[m][dc] = mfma16(pa[m], vf, o[m][dc]);
    }
  };

  auto compute = [&](int buf, int kb) {
    const int k0 = kb * 64;
    if (k0 > qw + 31) return;  // fully masked for this wave (wave-uniform)
    const unsigned short* Kb = &lK[buf][0];

    // S^T = mfma(K, Q): D[key=4g+r (+16kf)][q=c (+16m)]
    f32x4 s[2][4];
#pragma unroll
    for (int kf = 0; kf < 4; ++kf) {
      const bf16x8 ka = *(const bf16x8*)(Kb + (g * 64 + kf * 16 + c) * 8);
      const bf16x8 kb2 = *(const bf16x8*)(Kb + ((4 + g) * 64 + kf * 16 + c) * 8);
#pragma unroll
      for (int m = 0; m < 2; ++m) {
        f32x4 a = {};
        a = mfma16(ka, qf[m][0], a);
        a = mfma16(kb2, qf[m][1], a);
        s[m][kf] = a;
      }
    }
    // causal mask (only on diagonal-touching frags; conditions wave-uniform)
#pragma unroll
    for (int m = 0; m < 2; ++m)
#pragma unroll
      for (int kf = 0; kf < 4; ++kf)
        if (k0 + kf * 16 + 15 > qw + m * 16) {
#pragma unroll
          for (int r = 0; r < 4; ++r)
            if (k0 + kf * 16 + 4 * g + r > qw + m * 16 + c) s[m][kf][r] = -INFINITY;
        }
    // online softmax in log2-domain (scale folded into Q). Stats live at q=c,
    // uniform across the 4 g-lanes after the xor-16/32 reduction.
#pragma unroll
    for (int m = 0; m < 2; ++m) {
      float tmax = s[m][0][0];
#pragma unroll
      for (int kf = 0; kf < 4; ++kf)
#pragma unroll
        for (int r = 0; r < 4; ++r) tmax = fmaxf(tmax, s[m][kf][r]);
      tmax = fmaxf(tmax, __shfl_xor(tmax, 16));
      tmax = fmaxf(tmax, __shfl_xor(tmax, 32));
      const float mold = mrun[m];
      float mt;
      if (__all(tmax - mold <= 8.f)) {       // defer-max (T13): skip rescale
        mt = mold;
      } else {
        mt = fmaxf(mold, tmax);
        const float alpha = exp2f(mold - mt);
        mrun[m] = mt;
        lrun[m] *= alpha;
#pragma unroll
        for (int r = 0; r < 4; ++r) {
          // o rows are q=4g+r; alpha lives at q=c — redistribute via shfl
          const float ao = __shfl(alpha, (lane & 48) + ((lane & 48) >> 2) + r);
#pragma unroll
          for (int dc = 0; dc < 4; ++dc) o[m][dc][r] *= ao;
        }
      }
      float rs = 0.f;
#pragma unroll
      for (int kf = 0; kf < 4; ++kf)
#pragma unroll
        for (int r = 0; r < 4; ++r) {
          const float p = exp2f(s[m][kf][r] - mt);
          s[m][kf][r] = p;
          rs += p;
        }
      rs += __shfl_xor(rs, 16);
      rs += __shfl_xor(rs, 32);
      lrun[m] += rs;
    }
    // PV via hardware transpose reads of V subtiles
    const __attribute__((address_space(3))) unsigned short* vp =
        (const __attribute__((address_space(3))) unsigned short*)&lV[buf][0] + lane * 4;
    {
      u32x2 tr[4][2];
      TRRD(tr[0][0], "0");    TRRD(tr[0][1], "512");
      TRRD(tr[1][0], "2048"); TRRD(tr[1][1], "2560");
      TRRD(tr[2][0], "4096"); TRRD(tr[2][1], "4608");
      TRRD(tr[3][0], "6144"); TRRD(tr[3][1], "6656");
      asm volatile("s_waitcnt lgkmcnt(0)" ::: "memory");
      __builtin_amdgcn_sched_barrier(0);
      pv_mma(s, tr, 0);
    }
    {
      u32x2 tr[4][2];
      TRRD(tr[0][0], "1024"); TRRD(tr[0][1], "1536");
      TRRD(tr[1][0], "3072"); TRRD(tr[1][1], "3584");
      TRRD(tr[2][0], "5120"); TRRD(tr[2][1], "5632");
      TRRD(tr[3][0], "7168"); TRRD(tr[3][1], "7680");
      asm volatile("s_waitcnt lgkmcnt(0)" ::: "memory");
      __builtin_amdgcn_sched_barrier(0);
      pv_mma(s, tr, 1);
    }
  };

  // 2-phase pipeline: stage(t+1) in flight while computing t
  STAGE(0, 0);
  asm volatile("s_waitcnt vmcnt(0)" ::: "memory");
  __syncthreads();
  int cur = 0;
  for (int kb = 0; kb < nkb - 1; ++kb) {
    STAGE(cur ^ 1, kb + 1);
    compute(cur, kb);
    asm volatile("s_waitcnt vmcnt(0)" ::: "memory");
    __syncthreads();
    cur ^= 1;
  }
  compute(cur, nkb - 1);

  // epilogue: normalize and store
#pragma unroll
  for (int m = 0; m < 2; ++m)
#pragma unroll
    for (int r = 0; r < 4; ++r) {
      const float li = __shfl(lrun[m], (lane & 48) + ((lane & 48) >> 2) + r);
      const float inv = 1.f / li;
      const int q = qw + m * 16 + 4 * g + r;
#pragma unroll
      for (int dc = 0; dc < 4; ++dc)
        y[(rb + q) * 1024 + hc * 64 + dc * 16 + c] = f2bu(o[m][dc][r] * inv);
    }
#undef STAGE
#undef TRRD
}

// ---------------- launch ----------------
extern "C" void kernel_launch(void* const* d_in, const int* in_sizes, int n_in,
                              void* d_out, int out_size, void* d_ws, size_t ws_size,
                              hipStream_t stream) {
  (void)in_sizes; (void)n_in; (void)out_size; (void)ws_size;
  const float* x     = (const float*)d_in[0];
  const float* w_qkv = (const float*)d_in[1];
  const float* b_qkv = (const float*)d_in[2];
  const float* w_out = (const float*)d_in[3];
  const float* b_out = (const float*)d_in[4];
  float* out = (float*)d_out;

  char* ws = (char*)d_ws;
  unsigned short* x_bf  = (unsigned short*)(ws);                        // 16 MB (reused for y)
  unsigned short* wqkvT = (unsigned short*)(ws + (size_t)16 * 1048576); // 6 MB
  unsigned short* woutT = (unsigned short*)(ws + (size_t)22 * 1048576); // 2 MB
  unsigned short* qkv   = (unsigned short*)(ws + (size_t)24 * 1048576); // 48 MB -> total 72 MB

  // prep (Q weight columns pre-scaled by ATT_C)
  k_cast_bf16<<<dim3((MM * DD) / (256 * 8)), 256, 0, stream>>>(x, x_bf, MM * DD);
  k_transpose_bf16<<<dim3(3 * DD / 32, DD / 32), 256, 0, stream>>>(w_qkv, wqkvT, DD, 3 * DD,
                                                                   ATT_C, DD);
  k_transpose_bf16<<<dim3(DD / 32, DD / 32), 256, 0, stream>>>(w_out, woutT, DD, DD, 1.f, 0);

  // QKV projection: [8192,3072] bf16
  k_gemm_bt<0><<<dim3(3 * DD / 128, MM / 128), 256, 0, stream>>>(
      x_bf, wqkvT, b_qkv, qkv, MM, 3 * DD, DD, DD);

  // causal attention -> y (bf16, reuses x_bf region)
  k_attn<<<dim3(SS / 128, BB * HH), 256, 0, stream>>>(qkv, x_bf);

  // output projection: fp32 out
  k_gemm_bt<1><<<dim3(DD / 128, MM / 128), 256, 0, stream>>>(
      x_bf, woutT, b_out, out, MM, DD, DD, 0);
}